// Round 1
// baseline (3609.407 us; speedup 1.0000x reference)
//
#include <hip/hip_runtime.h>
#include <hip/hip_bf16.h>

#define FMPX 19
#define NPOS 361
#define CCH  512
#define NB   16
#define NCLS 20
#define CONF_T 0.001f
#define NMS_TH 0.6f
#define BSCALE (32.0f/608.0f)

#define SC_OFF   (NB*NPOS*4)
#define CLS_OFF  (SC_OFF + NB*NPOS)
#define KEEP_OFF (CLS_OFF + NB*NPOS)

#define CI_T 16
#define CO_T 64
#define RT   4
#define WP   20

// ---------- weight repack: wT[tap][ci][co] = w[co][ci][tap] ----------
__global__ void repack_w_k(const float* __restrict__ w, float* __restrict__ wT) {
  __shared__ float s[64][145];
  int co0 = blockIdx.x * 64, ci0 = blockIdx.y * 16;
  for (int i = threadIdx.x; i < 64 * 144; i += 256) {
    int co_l = i / 144, r = i % 144;
    s[co_l][r] = w[(size_t)(co0 + co_l) * CCH * 9 + (size_t)ci0 * 9 + r];
  }
  __syncthreads();
  for (int i = threadIdx.x; i < 144 * 64; i += 256) {
    int co_l = i & 63;
    int r = i >> 6;             // 0..143
    int ci_l = r / 9, tap = r % 9;
    wT[((size_t)tap * CCH + ci0 + ci_l) * CCH + co0 + co_l] = s[co_l][ci_l * 9 + tap];
  }
}

// ---------- 3x3 conv + bias + leaky relu ----------
// block: 256 thr = 16 co-groups (4 consecutive co each) x 16 pos-threads (5 consecutive x each)
// tile: 64 co x (4 rows x 20 padded cols); grid (co_tiles=8, row_tiles=5, B=16)
__global__ __launch_bounds__(256) void conv3x3_k(
    const float* __restrict__ in, const float* __restrict__ wT,
    const float* __restrict__ bias, float* __restrict__ out)
{
  __shared__ __align__(16) float Xs[CI_T][124];       // idx = 1 + ry*20 + x; zeros pad edges
  __shared__ __align__(16) float Ws[CI_T][9][CO_T];
  int t  = threadIdx.x;
  int co0 = blockIdx.x * CO_T;
  int r0  = blockIdx.y * RT;
  int b   = blockIdx.z;
  int cg = t & 15;
  int pq = t >> 4;
  int rl = pq >> 2;
  int x0 = (pq & 3) * 5;

  float acc[4][5];
#pragma unroll
  for (int j = 0; j < 4; j++)
#pragma unroll
    for (int k2 = 0; k2 < 5; k2++) acc[j][k2] = 0.f;

  const float* inb = in + (size_t)b * CCH * NPOS;

  for (int ci0 = 0; ci0 < CCH; ci0 += CI_T) {
    __syncthreads();
    // stage input rows r0-1 .. r0+4, padded-row layout (col19=0, row pads=0)
    for (int i = t; i < CI_T * 6 * WP; i += 256) {
      int ci_l = i / (6 * WP);
      int rr = i % (6 * WP);
      int ry = rr / WP, x = rr % WP;
      int gr = r0 - 1 + ry;
      float v = 0.f;
      if (x < FMPX && (unsigned)gr < (unsigned)FMPX)
        v = inb[(size_t)(ci0 + ci_l) * NPOS + gr * FMPX + x];
      Xs[ci_l][1 + ry * WP + x] = v;
    }
    if (t < CI_T) { Xs[t][0] = 0.f; Xs[t][121] = 0.f; Xs[t][122] = 0.f; Xs[t][123] = 0.f; }
    // stage all 9 taps of weights for this ci chunk
    for (int i = t; i < CI_T * 9 * CO_T; i += 256) {
      int co_l = i & 63;
      int r = i >> 6;
      int ci_l = r / 9, tap = r % 9;
      Ws[ci_l][tap][co_l] = wT[((size_t)tap * CCH + ci0 + ci_l) * CCH + co0 + co_l];
    }
    __syncthreads();
    const int xbase = 1 + (rl + 1) * WP + x0;
    for (int ci = 0; ci < CI_T; ++ci) {
      const float* xr = &Xs[ci][xbase];
      const float* wr = &Ws[ci][0][cg * 4];
#pragma unroll
      for (int tap = 0; tap < 9; ++tap) {
        const int dy = tap / 3 - 1, dx = tap % 3 - 1;
        const float* xp = xr + (dy * WP + dx);
        float4 wv = *(const float4*)(wr + tap * CO_T);
        float xv0 = xp[0], xv1 = xp[1], xv2 = xp[2], xv3 = xp[3], xv4 = xp[4];
        acc[0][0] += wv.x * xv0; acc[0][1] += wv.x * xv1; acc[0][2] += wv.x * xv2; acc[0][3] += wv.x * xv3; acc[0][4] += wv.x * xv4;
        acc[1][0] += wv.y * xv0; acc[1][1] += wv.y * xv1; acc[1][2] += wv.y * xv2; acc[1][3] += wv.y * xv3; acc[1][4] += wv.y * xv4;
        acc[2][0] += wv.z * xv0; acc[2][1] += wv.z * xv1; acc[2][2] += wv.z * xv2; acc[2][3] += wv.z * xv3; acc[2][4] += wv.z * xv4;
        acc[3][0] += wv.w * xv0; acc[3][1] += wv.w * xv1; acc[3][2] += wv.w * xv2; acc[3][3] += wv.w * xv3; acc[3][4] += wv.w * xv4;
      }
    }
  }
  int y = r0 + rl;
#pragma unroll
  for (int j = 0; j < 4; j++) {
    int co = co0 + cg * 4 + j;
    float bb = bias[co];
#pragma unroll
    for (int k2 = 0; k2 < 5; k2++) {
      int x = x0 + k2;
      if (y < FMPX && x < FMPX) {
        float v = acc[j][k2] + bb;
        v = v > 0.f ? v : 0.1f * v;
        out[((size_t)b * CCH + co) * NPOS + y * FMPX + x] = v;
      }
    }
  }
}

// ---------- 1x1 head: dst[b][p][NOUT] ----------
template <int NOUT>
__global__ void head1x1_k(const float* __restrict__ feat, const float* __restrict__ w,
                          const float* __restrict__ bias, float* __restrict__ dst)
{
  int b = blockIdx.y, pt = blockIdx.x;
  int pl = threadIdx.x & 63, cg = threadIdx.x >> 6;
  int p = pt * 64 + pl;
  float acc[NOUT];
#pragma unroll
  for (int o = 0; o < NOUT; o++) acc[o] = 0.f;
  const float* fb = feat + (size_t)b * CCH * NPOS;
  if (p < NPOS) {
    for (int ci = cg * (CCH / 4); ci < (cg + 1) * (CCH / 4); ++ci) {
      float a = fb[(size_t)ci * NPOS + p];
#pragma unroll
      for (int o = 0; o < NOUT; o++) acc[o] += w[o * CCH + ci] * a;
    }
  }
  __shared__ float red[NOUT][4][64];
#pragma unroll
  for (int o = 0; o < NOUT; o++) red[o][cg][pl] = acc[o];
  __syncthreads();
  for (int s_i = threadIdx.x; s_i < NOUT * 64; s_i += 256) {
    int o = s_i >> 6, pl2 = s_i & 63;
    int p2 = pt * 64 + pl2;
    if (p2 < NPOS) {
      float v = red[o][0][pl2] + red[o][1][pl2] + red[o][2][pl2] + red[o][3][pl2] + bias[o];
      dst[(size_t)(b * NPOS + p2) * NOUT + o] = v;
    }
  }
}

// ---------- decode boxes + scores + argmax; writes boxes/sc/cls and zeroes keep ----------
__global__ void decode_k(const float* __restrict__ obj, const float* __restrict__ clsp,
                         const float* __restrict__ regp, float* __restrict__ outb)
{
  int i = blockIdx.x * 256 + threadIdx.x;
  if (i >= NB * NPOS) return;
  int p = i % NPOS;
  float gx = (float)(p % FMPX), gy = (float)(p / FMPX);
  float4 rg = *(const float4*)&regp[(size_t)i * 4];
  float cx = 1.f / (1.f + expf(-rg.x)) + gx;
  float cy = 1.f / (1.f + expf(-rg.y)) + gy;
  float whw = expf(rg.z), whh = expf(rg.w);
  float x1 = fminf(fmaxf((cx - whw * 0.5f) * BSCALE, 0.f), 1.f);
  float y1 = fminf(fmaxf((cy - whh * 0.5f) * BSCALE, 0.f), 1.f);
  float x2 = fminf(fmaxf((cx + whw * 0.5f) * BSCALE, 0.f), 1.f);
  float y2 = fminf(fmaxf((cy + whh * 0.5f) * BSCALE, 0.f), 1.f);
  outb[(size_t)i * 4 + 0] = x1; outb[(size_t)i * 4 + 1] = y1;
  outb[(size_t)i * 4 + 2] = x2; outb[(size_t)i * 4 + 3] = y2;

  float so = 1.f / (1.f + expf(-obj[i]));
  float cv[20];
  const float4* cp = (const float4*)&clsp[(size_t)i * 20];
#pragma unroll
  for (int q = 0; q < 5; q++) {
    float4 v4 = cp[q];
    cv[q * 4] = v4.x; cv[q * 4 + 1] = v4.y; cv[q * 4 + 2] = v4.z; cv[q * 4 + 3] = v4.w;
  }
  float mx = cv[0];
#pragma unroll
  for (int c = 1; c < 20; c++) mx = fmaxf(mx, cv[c]);
  float sum = 0.f;
#pragma unroll
  for (int c = 0; c < 20; c++) { cv[c] = expf(cv[c] - mx); sum += cv[c]; }
  float inv = so / sum;
  float best = -1.f; int bi = 0;
#pragma unroll
  for (int c = 0; c < 20; c++) { float s = cv[c] * inv; if (s > best) { best = s; bi = c; } }
  outb[SC_OFF + i] = best;
  outb[CLS_OFF + i] = (float)bi;
  outb[KEEP_OFF + i] = 0.f;
}

// ---------- per (batch,class) greedy NMS; one wave per block ----------
__device__ inline unsigned ordf(float f) {
  unsigned u = __float_as_uint(f);
  return (u & 0x80000000u) ? ~u : (u | 0x80000000u);
}

__global__ __launch_bounds__(64) void nms_k(const float* __restrict__ outb, float* __restrict__ keep_out)
{
  int b = blockIdx.x / NCLS, c = blockIdx.x % NCLS;
  int lane = threadIdx.x;
  __shared__ unsigned long long keys[512];
  __shared__ float bx1[384], by1[384], bx2[384], by2[384], bar[384];
  __shared__ unsigned kp[384];
  __shared__ int sj[384];

  for (int i = lane; i < 512; i += 64) {
    unsigned long long key = 0ULL;
    if (i < NPOS) {
      float sc = outb[SC_OFF + b * NPOS + i];
      int ci = (int)outb[CLS_OFF + b * NPOS + i];
      float s = (ci == c && sc >= CONF_T) ? sc : -1.0f;
      key = ((unsigned long long)ordf(s) << 32) | (unsigned)(~(unsigned)i);
    }
    keys[i] = key;
  }
  __syncthreads();
  for (int kk = 2; kk <= 512; kk <<= 1) {
    for (int jj = kk >> 1; jj > 0; jj >>= 1) {
      for (int i = lane; i < 512; i += 64) {
        int l2 = i ^ jj;
        if (l2 > i) {
          unsigned long long a = keys[i], bb2 = keys[l2];
          bool dir = (i & kk) == 0;
          bool sw = dir ? (a < bb2) : (a > bb2);
          if (sw) { keys[i] = bb2; keys[l2] = a; }
        }
      }
      __syncthreads();
    }
  }
  unsigned ordc = ordf(CONF_T);
  int nvalid = 0;
  for (int i = lane; i < 384; i += 64) {
    unsigned long long key = keys[i];
    unsigned hi = (unsigned)(key >> 32);
    int j = (int)(~(unsigned)key);
    bool valid = (key != 0ULL) && (hi >= ordc);
    kp[i] = valid ? 1u : 0u;
    if (valid) {
      const float* bp = &outb[(size_t)(b * NPOS + j) * 4];
      float x1 = bp[0], y1 = bp[1], x2 = bp[2], y2 = bp[3];
      bx1[i] = x1; by1[i] = y1; bx2[i] = x2; by2[i] = y2;
      bar[i] = (x2 - x1) * (y2 - y1);
      sj[i] = j;
    } else { bx1[i] = 0; by1[i] = 0; bx2[i] = 0; by2[i] = 0; bar[i] = 0; sj[i] = 0; }
    nvalid += __popcll(__ballot(valid));
  }
  __syncthreads();
  for (int i = 0; i < nvalid; ++i) {
    if (kp[i]) {
      float x1i = bx1[i], y1i = by1[i], x2i = bx2[i], y2i = by2[i], ai = bar[i];
      for (int j2 = i + 1 + lane; j2 < nvalid; j2 += 64) {
        if (kp[j2]) {
          float ww = fmaxf(1e-28f, fminf(x2i, bx2[j2]) - fmaxf(x1i, bx1[j2]));
          float hh = fmaxf(1e-28f, fminf(y2i, by2[j2]) - fmaxf(y1i, by1[j2]));
          float inter = ww * hh;
          float iou = inter / (ai + bar[j2] - inter + 1e-14f);
          if (iou > NMS_TH) kp[j2] = 0u;
        }
      }
    }
    __syncthreads();
  }
  for (int i = lane; i < 384; i += 64)
    if (kp[i]) keep_out[b * NPOS + sj[i]] = 1.0f;
}

extern "C" void kernel_launch(void* const* d_in, const int* in_sizes, int n_in,
                              void* d_out, int out_size, void* d_ws, size_t ws_size,
                              hipStream_t stream)
{
  const float* x      = (const float*)d_in[0];
  const float* w_cls1 = (const float*)d_in[1];  const float* b_cls1 = (const float*)d_in[2];
  const float* w_cls2 = (const float*)d_in[3];  const float* b_cls2 = (const float*)d_in[4];
  const float* w_reg1 = (const float*)d_in[5];  const float* b_reg1 = (const float*)d_in[6];
  const float* w_reg2 = (const float*)d_in[7];  const float* b_reg2 = (const float*)d_in[8];
  const float* w_reg3 = (const float*)d_in[9];  const float* b_reg3 = (const float*)d_in[10];
  const float* w_reg4 = (const float*)d_in[11]; const float* b_reg4 = (const float*)d_in[12];
  const float* w_obj  = (const float*)d_in[13]; const float* b_obj  = (const float*)d_in[14];
  const float* w_clsh = (const float*)d_in[15]; const float* b_clsh = (const float*)d_in[16];
  const float* w_regh = (const float*)d_in[17]; const float* b_regh = (const float*)d_in[18];
  float* outb = (float*)d_out;
  float* W = (float*)d_ws;
  const size_t ACT = (size_t)NB * CCH * NPOS;
  float* A    = W;
  float* Bb   = A + ACT;
  float* wT   = Bb + ACT;
  float* obj  = wT + (size_t)9 * CCH * CCH;
  float* regp = obj + NB * NPOS;
  float* clsp = regp + (size_t)NB * NPOS * 4;

  dim3 cgrid(8, 5, NB);
  dim3 rgrid(8, 32);

  auto conv = [&](const float* src, const float* wsrc, const float* bsrc, float* dst) {
    repack_w_k<<<rgrid, 256, 0, stream>>>(wsrc, wT);
    conv3x3_k<<<cgrid, 256, 0, stream>>>(src, wT, bsrc, dst);
  };
  // reg chain first (rf in Bb), then heads on rf, then cls chain reusing buffers
  conv(x,  w_reg1, b_reg1, A);
  conv(A,  w_reg2, b_reg2, Bb);
  conv(Bb, w_reg3, b_reg3, A);
  conv(A,  w_reg4, b_reg4, Bb);                       // rf = Bb
  head1x1_k<1><<<dim3(6, NB), 256, 0, stream>>>(Bb, w_obj,  b_obj,  obj);
  head1x1_k<4><<<dim3(6, NB), 256, 0, stream>>>(Bb, w_regh, b_regh, regp);
  conv(x, w_cls1, b_cls1, A);
  conv(A, w_cls2, b_cls2, Bb);                        // cf = Bb (rf no longer needed)
  head1x1_k<20><<<dim3(6, NB), 256, 0, stream>>>(Bb, w_clsh, b_clsh, clsp);
  decode_k<<<(NB * NPOS + 255) / 256, 256, 0, stream>>>(obj, clsp, regp, outb);
  nms_k<<<NB * NCLS, 64, 0, stream>>>(outb, outb + KEEP_OFF);
}

// Round 2
// 1756.273 us; speedup vs baseline: 2.0552x; 2.0552x over previous
//
#include <hip/hip_runtime.h>
#include <hip/hip_bf16.h>
#include <stdint.h>

typedef __bf16 bf16x8 __attribute__((ext_vector_type(8)));
typedef float  f32x4  __attribute__((ext_vector_type(4)));

#define FMPX 19
#define NPOS 361
#define PP   441
#define CCH  512
#define NB   16
#define NCLS 20
#define CONF_T 0.001f
#define NMS_TH 0.6f
#define BSCALE (32.0f/608.0f)

#define SC_OFF   (NB*NPOS*4)
#define CLS_OFF  (SC_OFF + NB*NPOS)
#define KEEP_OFF (CLS_OFF + NB*NPOS)

#define PLANE ((size_t)NB*PP*CCH)   // 3,612,672 elems per split plane

#define XBUFB 35840                 // bytes per X LDS buffer (35 insts * 1024)
#define WOFF  71680                 // W region offset in smem
#define SMEMB 108544

__device__ __forceinline__ void gl_lds16(const void* g, void* l) {
  __builtin_amdgcn_global_load_lds(
      (const __attribute__((address_space(1))) unsigned int*)g,
      (__attribute__((address_space(3))) unsigned int*)l, 16, 0, 0);
}
#define VMCNT0 asm volatile("s_waitcnt vmcnt(0)" ::: "memory")
#define LGKM0  asm volatile("s_waitcnt lgkmcnt(0)" ::: "memory")
#define BAR()  __builtin_amdgcn_s_barrier()
#define MFMA(A,B,C) C = __builtin_amdgcn_mfma_f32_16x16x32_bf16(A,B,C,0,0,0)

// ---------------- split x (fp32 NCHW -> 3 bf16 planes [b][ppos][ci]) -------
__global__ void split_x_k(const float* __restrict__ x, __bf16* __restrict__ Xd) {
  __shared__ float sx[64][65];
  int pt = blockIdx.x, cg = blockIdx.y, b = blockIdx.z;
  int p0 = pt*64, c0 = cg*64;
  int tid = threadIdx.x;
  for (int r = tid; r < 64*64; r += 256) {
    int i = r >> 6, j = r & 63;
    int p = p0 + j;
    sx[i][j] = (p < NPOS) ? x[((size_t)(b*CCH + c0 + i))*NPOS + p] : 0.f;
  }
  __syncthreads();
  for (int r = tid; r < 64*64; r += 256) {
    int pl = r >> 6, cl = r & 63;
    int p = p0 + pl;
    if (p < NPOS) {
      float v = sx[cl][pl];
      __bf16 hh = (__bf16)v; float r1 = v - (float)hh;
      __bf16 mm = (__bf16)r1; __bf16 ll = (__bf16)(r1 - (float)mm);
      int y = (unsigned)p / 19u;
      int pp = p + 2*y + 22;
      size_t o = ((size_t)b*PP + pp)*CCH + c0 + cl;
      Xd[o] = hh; Xd[PLANE + o] = mm; Xd[2*PLANE + o] = ll;
    }
  }
}

// ---------------- weight repack+split: w[co][ci][3][3] f32 ->
//   Wg 16B-units: [(sp*9+tap)*64 + cig][co] holding 8 bf16 (ci = cig*8..+8) --
__global__ void repack_k(const float* __restrict__ w, __bf16* __restrict__ Wg) {
  __shared__ float sw[128][72];
  int coq = blockIdx.x, cig = blockIdx.y;
  int co0 = coq*128;
  int tid = threadIdx.x;
  for (int r = tid; r < 128*18; r += 256) {
    int cl = r / 18, fq = r % 18;
    ((float4*)&sw[cl][0])[fq] =
      ((const float4*)(w + (size_t)(co0+cl)*4608 + (size_t)cig*72))[fq];
  }
  __syncthreads();
  for (int r = tid; r < 27*128; r += 256) {
    int cl = r & 127, u = r >> 7;
    int sp = u / 9, tp = u % 9;
    bf16x8 v;
#pragma unroll
    for (int j = 0; j < 8; ++j) {
      float vv = sw[cl][j*9 + tp];
      __bf16 hh = (__bf16)vv; float r1 = vv - (float)hh;
      __bf16 mm = (__bf16)r1;
      v[j] = (sp == 0) ? hh : (sp == 1) ? mm : (__bf16)(r1 - (float)mm);
    }
    *(bf16x8*)(Wg + (((size_t)(sp*9 + tp)*64 + cig)*CCH + co0 + cl)*8) = v;
  }
}

// ---------------- 3x3 conv via MFMA, bf16x3 6-product split ----------------
// grid 512: bid = (b*16+sl)*2+h ; block 256 (4 waves)
// wave tile: 3 m16-tiles x 32 co ; K-loop: 16 ci-chunks x 9 taps x 6 products
__global__ __launch_bounds__(256, 1) void conv3x3_mfma(
    const __bf16* __restrict__ Xs, const __bf16* __restrict__ Wg,
    const float* __restrict__ bias, __bf16* __restrict__ Xd)
{
  __shared__ __attribute__((aligned(16))) char smem[SMEMB];
  const int tid = threadIdx.x;
  const int bid = blockIdx.x;
  const int h = bid & 1, sl = (bid >> 1) & 15, b = bid >> 5;
  const int lane = tid & 63;
  const int w = __builtin_amdgcn_readfirstlane(tid >> 6);
  const int l15 = lane & 15, kg = lane >> 4;
  const int pprow0 = h ? 9 : 0;
  const int co_g0 = sl * 32;
  const int goffs[9] = {-22,-21,-20,-1,0,1,20,21,22};

  // per-m-tile constants
  int rlb0, rlb1, rlb2; int gp0, gp1, gp2;
  {
#pragma unroll
    for (int mt = 0; mt < 3; ++mt) {
      int p = h*192 + (w*3 + mt)*16 + l15;
      int pc = p > 360 ? 360 : p;
      int y = (unsigned)pc / 19u;
      int rl = (y + 1 - pprow0)*21 + (pc - y*19) + 1;
      int gp = pc + 2*y + 22;
      if (mt == 0) { rlb0 = rl; gp0 = gp; }
      else if (mt == 1) { rlb1 = rl; gp1 = gp; }
      else { rlb2 = rl; gp2 = gp; }
    }
  }
  const __bf16* xlbase = Xs + 2*PLANE + (size_t)b*PP*CCH;

  // X staging src pointers (per wave up to 9 insts; 35 total)
  const __bf16* xsrc[9];
#pragma unroll
  for (int j = 0; j < 9; ++j) {
    int i = w + 4*j;
    int n = i*64 + lane; if (n > 2183) n = 2183;
    int sp = n / 1092; int r1 = n % 1092;
    int kgs = r1 / 273; int r = r1 % 273;
    int rr = r / 21, cc = r % 21;
    int gpp = (pprow0 + rr)*21 + cc; if (gpp > 440) gpp = 440;
    xsrc[j] = Xs + (size_t)sp*PLANE + ((size_t)b*PP + gpp)*CCH + kgs*8;
  }
  // W staging per-thread constants
  const int wsp = tid >> 7, wkg = (tid >> 5) & 3, wco = tid & 31;

  // A/B LDS row offsets
  const int ar00 = (0*4 + kg)*273 + rlb0, ar01 = (0*4 + kg)*273 + rlb1, ar02 = (0*4 + kg)*273 + rlb2;
  const int ar10 = (1*4 + kg)*273 + rlb0, ar11 = (1*4 + kg)*273 + rlb1, ar12 = (1*4 + kg)*273 + rlb2;
  const int bo0 = ((0*4 + kg)*32 + l15)*16;
  const int bo1 = ((1*4 + kg)*32 + l15)*16;

  f32x4 acc[3][2] = {};

  auto stageX = [&](int c1, int buf) {
#pragma unroll
    for (int j = 0; j < 9; ++j)
      if (w + 4*j < 35)
        gl_lds16(xsrc[j] + (size_t)c1*32, smem + buf*XBUFB + (w + 4*j)*1024);
  };
  auto stageW = [&](int c1, int t) {
    gl_lds16(Wg + (((size_t)(wsp*9 + t)*64 + c1*4 + wkg)*CCH + co_g0 + wco)*8,
             smem + WOFF + t*4096 + w*1024);
  };
  auto ldstreams = [&](int cc, int tt, bf16x8& A0, bf16x8& A1, bf16x8& A2,
                       bf16x8& B0, bf16x8& B1) {
    int go = goffs[tt];
    A0 = *(const bf16x8*)(xlbase + (size_t)(gp0 + go)*CCH + cc*32 + kg*8);
    A1 = *(const bf16x8*)(xlbase + (size_t)(gp1 + go)*CCH + cc*32 + kg*8);
    A2 = *(const bf16x8*)(xlbase + (size_t)(gp2 + go)*CCH + cc*32 + kg*8);
    const __bf16* wb = Wg + ((size_t)((18 + tt)*64 + cc*4 + kg)*CCH + co_g0)*8;
    B0 = *(const bf16x8*)(wb + (size_t)l15*8);
    B1 = *(const bf16x8*)(wb + (size_t)(l15 + 16)*8);
  };

  // prologue
  stageX(0, 0);
#pragma unroll
  for (int t = 0; t < 9; ++t) stageW(0, t);
  VMCNT0; BAR();

  bf16x8 Al0, Al1, Al2, Bl0, Bl1;
  ldstreams(0, 0, Al0, Al1, Al2, Bl0, Bl1);

  int cb = 0;
  for (int c = 0; c < 16; ++c) {
    if (c < 15) stageX(c + 1, cb ^ 1);
    const char* Xc = smem + cb*XBUFB;
#pragma unroll
    for (int t = 0; t < 9; ++t) {
      bf16x8 nA0 = Al0, nA1 = Al1, nA2 = Al2, nB0 = Bl0, nB1 = Bl1;
      if (t < 8) ldstreams(c, t + 1, nA0, nA1, nA2, nB0, nB1);
      else if (c < 15) ldstreams(c + 1, 0, nA0, nA1, nA2, nB0, nB1);

      const int go = goffs[t];
      const char* Wt = smem + WOFF + t*4096;
      bf16x8 Bh0 = *(const bf16x8*)(Wt + bo0);
      bf16x8 Bh1 = *(const bf16x8*)(Wt + bo0 + 256);
      bf16x8 Bm0 = *(const bf16x8*)(Wt + bo1);
      bf16x8 Bm1 = *(const bf16x8*)(Wt + bo1 + 256);
      bf16x8 Ah0 = *(const bf16x8*)(Xc + (size_t)(ar00 + go)*16);
      bf16x8 Ah1 = *(const bf16x8*)(Xc + (size_t)(ar01 + go)*16);
      bf16x8 Ah2 = *(const bf16x8*)(Xc + (size_t)(ar02 + go)*16);
      bf16x8 Am0 = *(const bf16x8*)(Xc + (size_t)(ar10 + go)*16);
      bf16x8 Am1 = *(const bf16x8*)(Xc + (size_t)(ar11 + go)*16);
      bf16x8 Am2 = *(const bf16x8*)(Xc + (size_t)(ar12 + go)*16);

      MFMA(Ah0, Bh0, acc[0][0]); MFMA(Ah0, Bh1, acc[0][1]);
      MFMA(Ah1, Bh0, acc[1][0]); MFMA(Ah1, Bh1, acc[1][1]);
      MFMA(Ah2, Bh0, acc[2][0]); MFMA(Ah2, Bh1, acc[2][1]);
      MFMA(Ah0, Bm0, acc[0][0]); MFMA(Ah0, Bm1, acc[0][1]);
      MFMA(Ah1, Bm0, acc[1][0]); MFMA(Ah1, Bm1, acc[1][1]);
      MFMA(Ah2, Bm0, acc[2][0]); MFMA(Ah2, Bm1, acc[2][1]);
      MFMA(Ah0, Bl0, acc[0][0]); MFMA(Ah0, Bl1, acc[0][1]);
      MFMA(Ah1, Bl0, acc[1][0]); MFMA(Ah1, Bl1, acc[1][1]);
      MFMA(Ah2, Bl0, acc[2][0]); MFMA(Ah2, Bl1, acc[2][1]);
      MFMA(Am0, Bh0, acc[0][0]); MFMA(Am0, Bh1, acc[0][1]);
      MFMA(Am1, Bh0, acc[1][0]); MFMA(Am1, Bh1, acc[1][1]);
      MFMA(Am2, Bh0, acc[2][0]); MFMA(Am2, Bh1, acc[2][1]);
      MFMA(Am0, Bm0, acc[0][0]); MFMA(Am0, Bm1, acc[0][1]);
      MFMA(Am1, Bm0, acc[1][0]); MFMA(Am1, Bm1, acc[1][1]);
      MFMA(Am2, Bm0, acc[2][0]); MFMA(Am2, Bm1, acc[2][1]);
      MFMA(Al0, Bh0, acc[0][0]); MFMA(Al0, Bh1, acc[0][1]);
      MFMA(Al1, Bh0, acc[1][0]); MFMA(Al1, Bh1, acc[1][1]);
      MFMA(Al2, Bh0, acc[2][0]); MFMA(Al2, Bh1, acc[2][1]);

      if (t == 2 || t == 5 || t == 8) {
        LGKM0; BAR();
        if (c < 15) { stageW(c + 1, t - 2); stageW(c + 1, t - 1); stageW(c + 1, t); }
      }
      Al0 = nA0; Al1 = nA1; Al2 = nA2; Bl0 = nB0; Bl1 = nB1;
    }
    VMCNT0; BAR();
    cb ^= 1;
  }

  // epilogue: bias + leaky relu + bf16x3 split + store [b][ppos][co]
  float bia0 = bias[co_g0 + l15];
  float bia1 = bias[co_g0 + l15 + 16];
#pragma unroll
  for (int mt = 0; mt < 3; ++mt) {
    int pb = h*192 + (w*3 + mt)*16 + kg*4;
#pragma unroll
    for (int q = 0; q < 4; ++q) {
      int pr = pb + q;
      if (pr <= 360) {
        int y = (unsigned)pr / 19u;
        size_t row = ((size_t)b*PP + (pr + 2*y + 22))*CCH + co_g0;
#pragma unroll
        for (int nf = 0; nf < 2; ++nf) {
          float v = acc[mt][nf][q] + (nf ? bia1 : bia0);
          v = v > 0.f ? v : 0.1f*v;
          __bf16 hh = (__bf16)v; float r1 = v - (float)hh;
          __bf16 mm = (__bf16)r1; __bf16 ll = (__bf16)(r1 - (float)mm);
          size_t o = row + l15 + nf*16;
          Xd[o] = hh; Xd[PLANE + o] = mm; Xd[2*PLANE + o] = ll;
        }
      }
    }
  }
}

// ---------------- 1x1 heads (read split planes, fp32 math) ----------------
__global__ __launch_bounds__(256) void head_rf_k(
    const __bf16* __restrict__ F, const float* __restrict__ wobj,
    const float* __restrict__ bobj, const float* __restrict__ wreg,
    const float* __restrict__ breg, float* __restrict__ obj, float* __restrict__ regp)
{
  int gw = blockIdx.x*4 + (threadIdx.x >> 6);
  if (gw >= NB*NPOS) return;
  int lane = threadIdx.x & 63;
  int b = gw / NPOS, p = gw % NPOS;
  int y = (unsigned)p / 19u;
  int pp = p + 2*y + 22;
  size_t base = ((size_t)b*PP + pp)*CCH;
  float f[8];
#pragma unroll
  for (int it = 0; it < 8; ++it) {
    size_t o = base + lane + it*64;
    f[it] = (float)F[o] + (float)F[PLANE + o] + (float)F[2*PLANE + o];
  }
#pragma unroll
  for (int o = 0; o < 5; ++o) {
    const float* wp = o ? (wreg + (o-1)*CCH) : wobj;
    float s = 0.f;
#pragma unroll
    for (int it = 0; it < 8; ++it) s += wp[lane + it*64]*f[it];
    for (int d = 32; d; d >>= 1) s += __shfl_xor(s, d);
    if (lane == 0) {
      if (o == 0) obj[gw] = s + bobj[0];
      else regp[(size_t)gw*4 + (o-1)] = s + breg[o-1];
    }
  }
}

__global__ __launch_bounds__(256) void head_cls_k(
    const __bf16* __restrict__ F, const float* __restrict__ wcls,
    const float* __restrict__ bcls, float* __restrict__ clsp)
{
  int gw = blockIdx.x*4 + (threadIdx.x >> 6);
  if (gw >= NB*NPOS) return;
  int lane = threadIdx.x & 63;
  int b = gw / NPOS, p = gw % NPOS;
  int y = (unsigned)p / 19u;
  int pp = p + 2*y + 22;
  size_t base = ((size_t)b*PP + pp)*CCH;
  float f[8];
#pragma unroll
  for (int it = 0; it < 8; ++it) {
    size_t o = base + lane + it*64;
    f[it] = (float)F[o] + (float)F[PLANE + o] + (float)F[2*PLANE + o];
  }
#pragma unroll
  for (int o = 0; o < 20; ++o) {
    const float* wp = wcls + o*CCH;
    float s = 0.f;
#pragma unroll
    for (int it = 0; it < 8; ++it) s += wp[lane + it*64]*f[it];
    for (int d = 32; d; d >>= 1) s += __shfl_xor(s, d);
    if (lane == 0) clsp[(size_t)gw*20 + o] = s + bcls[o];
  }
}

// ---------------- decode boxes + scores + argmax -------------------------
__global__ void decode_k(const float* __restrict__ obj, const float* __restrict__ clsp,
                         const float* __restrict__ regp, float* __restrict__ outb)
{
  int i = blockIdx.x * 256 + threadIdx.x;
  if (i >= NB * NPOS) return;
  int p = i % NPOS;
  float gx = (float)(p % FMPX), gy = (float)(p / FMPX);
  float4 rg = *(const float4*)&regp[(size_t)i * 4];
  float cx = 1.f / (1.f + expf(-rg.x)) + gx;
  float cy = 1.f / (1.f + expf(-rg.y)) + gy;
  float whw = expf(rg.z), whh = expf(rg.w);
  float x1 = fminf(fmaxf((cx - whw * 0.5f) * BSCALE, 0.f), 1.f);
  float y1 = fminf(fmaxf((cy - whh * 0.5f) * BSCALE, 0.f), 1.f);
  float x2 = fminf(fmaxf((cx + whw * 0.5f) * BSCALE, 0.f), 1.f);
  float y2 = fminf(fmaxf((cy + whh * 0.5f) * BSCALE, 0.f), 1.f);
  outb[(size_t)i * 4 + 0] = x1; outb[(size_t)i * 4 + 1] = y1;
  outb[(size_t)i * 4 + 2] = x2; outb[(size_t)i * 4 + 3] = y2;

  float so = 1.f / (1.f + expf(-obj[i]));
  float cv[20];
  const float4* cp = (const float4*)&clsp[(size_t)i * 20];
#pragma unroll
  for (int q = 0; q < 5; q++) {
    float4 v4 = cp[q];
    cv[q * 4] = v4.x; cv[q * 4 + 1] = v4.y; cv[q * 4 + 2] = v4.z; cv[q * 4 + 3] = v4.w;
  }
  float mx = cv[0];
#pragma unroll
  for (int c = 1; c < 20; c++) mx = fmaxf(mx, cv[c]);
  float sum = 0.f;
#pragma unroll
  for (int c = 0; c < 20; c++) { cv[c] = expf(cv[c] - mx); sum += cv[c]; }
  float inv = so / sum;
  float best = -1.f; int bi = 0;
#pragma unroll
  for (int c = 0; c < 20; c++) { float s = cv[c] * inv; if (s > best) { best = s; bi = c; } }
  outb[SC_OFF + i] = best;
  outb[CLS_OFF + i] = (float)bi;
  outb[KEEP_OFF + i] = 0.f;
}

// ---------------- per (batch,class) greedy NMS ----------------------------
__device__ inline unsigned ordf(float f) {
  unsigned u = __float_as_uint(f);
  return (u & 0x80000000u) ? ~u : (u | 0x80000000u);
}

__global__ __launch_bounds__(64) void nms_k(const float* __restrict__ outb, float* __restrict__ keep_out)
{
  int b = blockIdx.x / NCLS, c = blockIdx.x % NCLS;
  int lane = threadIdx.x;
  __shared__ unsigned long long keys[512];
  __shared__ float bx1[384], by1[384], bx2[384], by2[384], bar[384];
  __shared__ unsigned kp[384];
  __shared__ int sj[384];

  for (int i = lane; i < 512; i += 64) {
    unsigned long long key = 0ULL;
    if (i < NPOS) {
      float sc = outb[SC_OFF + b * NPOS + i];
      int ci = (int)outb[CLS_OFF + b * NPOS + i];
      float s = (ci == c && sc >= CONF_T) ? sc : -1.0f;
      key = ((unsigned long long)ordf(s) << 32) | (unsigned)(~(unsigned)i);
    }
    keys[i] = key;
  }
  __syncthreads();
  for (int kk = 2; kk <= 512; kk <<= 1) {
    for (int jj = kk >> 1; jj > 0; jj >>= 1) {
      for (int i = lane; i < 512; i += 64) {
        int l2 = i ^ jj;
        if (l2 > i) {
          unsigned long long a = keys[i], bb2 = keys[l2];
          bool dir = (i & kk) == 0;
          bool sw = dir ? (a < bb2) : (a > bb2);
          if (sw) { keys[i] = bb2; keys[l2] = a; }
        }
      }
      __syncthreads();
    }
  }
  unsigned ordc = ordf(CONF_T);
  int nvalid = 0;
  for (int i = lane; i < 384; i += 64) {
    unsigned long long key = keys[i];
    unsigned hi = (unsigned)(key >> 32);
    int j = (int)(~(unsigned)key);
    bool valid = (key != 0ULL) && (hi >= ordc);
    kp[i] = valid ? 1u : 0u;
    if (valid) {
      const float* bp = &outb[(size_t)(b * NPOS + j) * 4];
      float x1 = bp[0], y1 = bp[1], x2 = bp[2], y2 = bp[3];
      bx1[i] = x1; by1[i] = y1; bx2[i] = x2; by2[i] = y2;
      bar[i] = (x2 - x1) * (y2 - y1);
      sj[i] = j;
    } else { bx1[i] = 0; by1[i] = 0; bx2[i] = 0; by2[i] = 0; bar[i] = 0; sj[i] = 0; }
    nvalid += __popcll(__ballot(valid));
  }
  __syncthreads();
  for (int i = 0; i < nvalid; ++i) {
    if (kp[i]) {
      float x1i = bx1[i], y1i = by1[i], x2i = bx2[i], y2i = by2[i], ai = bar[i];
      for (int j2 = i + 1 + lane; j2 < nvalid; j2 += 64) {
        if (kp[j2]) {
          float ww = fmaxf(1e-28f, fminf(x2i, bx2[j2]) - fmaxf(x1i, bx1[j2]));
          float hh = fmaxf(1e-28f, fminf(y2i, by2[j2]) - fmaxf(y1i, by1[j2]));
          float inter = ww * hh;
          float iou = inter / (ai + bar[j2] - inter + 1e-14f);
          if (iou > NMS_TH) kp[j2] = 0u;
        }
      }
    }
    __syncthreads();
  }
  for (int i = lane; i < 384; i += 64)
    if (kp[i]) keep_out[b * NPOS + sj[i]] = 1.0f;
}

extern "C" void kernel_launch(void* const* d_in, const int* in_sizes, int n_in,
                              void* d_out, int out_size, void* d_ws, size_t ws_size,
                              hipStream_t stream)
{
  const float* x      = (const float*)d_in[0];
  const float* w_cls1 = (const float*)d_in[1];  const float* b_cls1 = (const float*)d_in[2];
  const float* w_cls2 = (const float*)d_in[3];  const float* b_cls2 = (const float*)d_in[4];
  const float* w_reg1 = (const float*)d_in[5];  const float* b_reg1 = (const float*)d_in[6];
  const float* w_reg2 = (const float*)d_in[7];  const float* b_reg2 = (const float*)d_in[8];
  const float* w_reg3 = (const float*)d_in[9];  const float* b_reg3 = (const float*)d_in[10];
  const float* w_reg4 = (const float*)d_in[11]; const float* b_reg4 = (const float*)d_in[12];
  const float* w_obj  = (const float*)d_in[13]; const float* b_obj  = (const float*)d_in[14];
  const float* w_clsh = (const float*)d_in[15]; const float* b_clsh = (const float*)d_in[16];
  const float* w_regh = (const float*)d_in[17]; const float* b_regh = (const float*)d_in[18];
  float* outb = (float*)d_out;

  __bf16* XsA = (__bf16*)d_ws;
  __bf16* XsB = XsA + 3*PLANE;
  __bf16* Wg  = XsB + 3*PLANE;
  float* obj  = (float*)((char*)d_ws + (size_t)12*PLANE*2 /*6 planes bf16*/ + (size_t)3*9*64*CCH*16);
  float* regp = obj + NB*NPOS;
  float* clsp = regp + NB*NPOS*4;

  // zero both split-activation buffers (halo must be 0; ws is poisoned)
  hipMemsetAsync(d_ws, 0, (size_t)6*PLANE*2, stream);

  dim3 sgrid(6, 8, NB);
  dim3 rgrid(4, 64);

  auto conv = [&](const float* wsrc, const float* bsrc, const __bf16* src, __bf16* dst) {
    repack_k<<<rgrid, 256, 0, stream>>>(wsrc, Wg);
    conv3x3_mfma<<<512, 256, 0, stream>>>(src, Wg, bsrc, dst);
  };

  split_x_k<<<sgrid, 256, 0, stream>>>(x, XsA);
  conv(w_reg1, b_reg1, XsA, XsB);
  conv(w_reg2, b_reg2, XsB, XsA);
  conv(w_reg3, b_reg3, XsA, XsB);
  conv(w_reg4, b_reg4, XsB, XsA);                    // rf = XsA
  head_rf_k<<<1444, 256, 0, stream>>>(XsA, w_obj, b_obj, w_regh, b_regh, obj, regp);
  split_x_k<<<sgrid, 256, 0, stream>>>(x, XsB);      // re-split x
  conv(w_cls1, b_cls1, XsB, XsA);
  conv(w_cls2, b_cls2, XsA, XsB);                    // cf = XsB
  head_cls_k<<<1444, 256, 0, stream>>>(XsB, w_clsh, b_clsh, clsp);
  decode_k<<<(NB * NPOS + 255) / 256, 256, 0, stream>>>(obj, clsp, regp, outb);
  nms_k<<<NB * NCLS, 64, 0, stream>>>(outb, outb + KEEP_OFF);
}

// Round 3
// 1201.640 us; speedup vs baseline: 3.0037x; 1.4616x over previous
//
#include <hip/hip_runtime.h>
#include <hip/hip_bf16.h>
#include <stdint.h>

typedef __bf16 bf16x8 __attribute__((ext_vector_type(8)));
typedef float  f32x16 __attribute__((ext_vector_type(16)));

#define FMPX 19
#define NPOS 361
#define CCH  512
#define NB   16
#define NCLS 20
#define CONF_T 0.001f
#define NMS_TH 0.6f
#define BSCALE (32.0f/608.0f)

#define SC_OFF   (NB*NPOS*4)
#define CLS_OFF  (SC_OFF + NB*NPOS)
#define KEEP_OFF (CLS_OFF + NB*NPOS)

#define GSTR  3528                     // 441 rows * 8 ci elems
#define PLANE ((size_t)3612672)        // 16 b * 64 g * 3528
#define XBUF  42336                    // 3 pl * 2 kh * 441 rows * 16B
#define WBUF  27648                    // 3 pl * 9 tap * 2 kh * 32 co * 16B
#define WOFF  84672                    // 2*XBUF
#define SMEMB 139968                   // 2*XBUF + 2*WBUF

__device__ __forceinline__ void gl_lds16(const void* g, void* l) {
  __builtin_amdgcn_global_load_lds(
      (const __attribute__((address_space(1))) unsigned int*)g,
      (__attribute__((address_space(3))) unsigned int*)l, 16, 0, 0);
}
#define MFMA32(A,B,C) __builtin_amdgcn_mfma_f32_32x32x16_bf16(A,B,C,0,0,0)

// ---------------- split x: f32 NCHW -> 3 bf16 planes [pl][b][g][row441][8ci]
__global__ void split_x_k(const float* __restrict__ x, __bf16* __restrict__ Xd) {
  __shared__ float sx[8][368];
  int g = blockIdx.x, b = blockIdx.y;
  int tid = threadIdx.x;
  for (int i = tid; i < 8*361; i += 256) {
    int ci = i / 361, p = i - ci*361;
    sx[ci][p] = x[((size_t)b*CCH + g*8 + ci)*NPOS + p];
  }
  __syncthreads();
  for (int row = tid; row < 441; row += 256) {
    int y = row/21, xx = row - y*21;
    bf16x8 oh = {}, om = {}, ol = {};
    if (y >= 1 && y <= 19 && xx >= 1 && xx <= 19) {
      int p = (y-1)*19 + xx - 1;
#pragma unroll
      for (int j = 0; j < 8; ++j) {
        float v = sx[j][p];
        __bf16 hh = (__bf16)v; float r1 = v - (float)hh;
        __bf16 mm = (__bf16)r1;
        oh[j] = hh; om[j] = mm; ol[j] = (__bf16)(r1 - (float)mm);
      }
    }
    size_t o = (((size_t)b)*64 + g)*GSTR + (size_t)row*8;
    *(bf16x8*)(Xd + o)           = oh;
    *(bf16x8*)(Xd + PLANE + o)   = om;
    *(bf16x8*)(Xd + 2*PLANE + o) = ol;
  }
}

// ---------------- weight repack+split: w[co][ci][3][3] f32 ->
//  Wg [slice16][pl3][tap9][chunk32][kh2][co32][8ci] bf16
__global__ void repack_k(const float* __restrict__ w, __bf16* __restrict__ Wg) {
  __shared__ float sw[32][145];
  int slice = blockIdx.x, chunk = blockIdx.y;
  int tid = threadIdx.x;
  for (int i = tid; i < 32*144; i += 256) {
    int cl = i / 144, r = i - cl*144;
    sw[cl][r] = w[((size_t)slice*32 + cl)*4608 + chunk*144 + r];
  }
  __syncthreads();
  for (int u = tid; u < 1728; u += 256) {
    int co = u & 31, kh = (u >> 5) & 1, pt = u >> 6;
    int tap = pt % 9, pl = pt / 9;
    bf16x8 o;
#pragma unroll
    for (int j = 0; j < 8; ++j) {
      float v = sw[co][(kh*8 + j)*9 + tap];
      __bf16 hh = (__bf16)v; float r1 = v - (float)hh;
      __bf16 mm = (__bf16)r1;
      o[j] = pl == 0 ? hh : (pl == 1 ? mm : (__bf16)(r1 - (float)mm));
    }
    *(bf16x8*)(Wg + ((((size_t)slice*3 + pl)*9 + tap)*32 + chunk)*512 + kh*256 + co*8) = o;
  }
}

// ---------------- 3x3 conv via 32x32x16 MFMA, bf16x3 6-product split -------
// grid 256: bid = slice*16 + b ; block 512 (8 waves = 4 pos-groups x 2 psplit)
__global__ __launch_bounds__(512, 2) void conv3x3_mfma(
    const __bf16* __restrict__ Xs, const __bf16* __restrict__ Wg,
    const float* __restrict__ bias, __bf16* __restrict__ Xd)
{
  __shared__ __attribute__((aligned(16))) char smem[SMEMB];
  const int tid = threadIdx.x;
  const int bid = blockIdx.x;
  const int b = bid & 15, slice = bid >> 4;
  const int lane = tid & 63;
  const int wq = __builtin_amdgcn_readfirstlane(tid >> 6);
  const int pg = wq >> 1, s = wq & 1;
  const int col = lane & 31, kh = lane >> 5;
  const int goffs[9] = {-22,-21,-20,-1,0,1,20,21,22};

  // A LDS byte offsets (plane 0, center tap) per m-tile
  int aoff[3];
#pragma unroll
  for (int mt = 0; mt < 3; ++mt) {
    int p = pg*96 + mt*32 + col; if (p > 360) p = 360;
    int pp = p + 2*(p/19) + 22;
    aoff[mt] = kh*7056 + pp*16;
  }
  const int boff = kh*512 + col*16;

  // staging source element offsets (chunk 0)
  int xsoff[6];
#pragma unroll
  for (int r = 0; r < 6; ++r) {
    int u = r*512 + tid; if (u > 2645) u = 2645;
    int pl = u / 882, rem = u - pl*882;
    int kh2 = rem / 441, row = rem - kh2*441;
    xsoff[r] = ((pl*16 + b)*64 + kh2)*GSTR + row*8;
  }
  int wsoff[4];
#pragma unroll
  for (int r = 0; r < 4; ++r) {
    int v = r*512 + tid; if (v > 1727) v = 1727;
    int co = v & 31, kh2 = (v >> 5) & 1, pt = v >> 6;
    int tap = pt % 9, pl = pt / 9;
    wsoff[r] = (((slice*3 + pl)*9 + tap)*32)*512 + kh2*256 + co*8;
  }

  auto stage = [&](int c, int buf) {
#pragma unroll
    for (int r = 0; r < 6; ++r)
      if (r*512 + tid < 2646)
        gl_lds16(Xs + xsoff[r] + c*7056, smem + buf*XBUF + (r*512 + wq*64)*16);
#pragma unroll
    for (int r = 0; r < 4; ++r)
      if (r*512 + tid < 1728)
        gl_lds16(Wg + wsoff[r] + c*512, smem + WOFF + buf*WBUF + (r*512 + wq*64)*16);
  };

  f32x16 acc0 = {}, acc1 = {}, acc2 = {};

  stage(0, 0);
  __syncthreads();

  for (int c = 0; c < 32; ++c) {
    if (c < 31) stage(c + 1, (c + 1) & 1);
    const char* X = smem + (c & 1)*XBUF;
    const char* W = smem + WOFF + (c & 1)*WBUF;
#pragma unroll
    for (int t = 0; t < 9; ++t) {
      const int go = goffs[t]*16;
      if (s == 0) {
        // products: Ah*Bh, Ah*Bm, Ah*Bl
        bf16x8 A0 = *(const bf16x8*)(X + aoff[0] + go);
        bf16x8 A1 = *(const bf16x8*)(X + aoff[1] + go);
        bf16x8 A2 = *(const bf16x8*)(X + aoff[2] + go);
        bf16x8 Bh = *(const bf16x8*)(W + t*1024 + boff);
        bf16x8 Bm = *(const bf16x8*)(W + 9216  + t*1024 + boff);
        bf16x8 Bl = *(const bf16x8*)(W + 18432 + t*1024 + boff);
        acc0 = MFMA32(A0, Bh, acc0); acc1 = MFMA32(A1, Bh, acc1); acc2 = MFMA32(A2, Bh, acc2);
        acc0 = MFMA32(A0, Bm, acc0); acc1 = MFMA32(A1, Bm, acc1); acc2 = MFMA32(A2, Bm, acc2);
        acc0 = MFMA32(A0, Bl, acc0); acc1 = MFMA32(A1, Bl, acc1); acc2 = MFMA32(A2, Bl, acc2);
      } else {
        // products: Am*Bh, Am*Bm, Al*Bh
        bf16x8 M0 = *(const bf16x8*)(X + 14112 + aoff[0] + go);
        bf16x8 M1 = *(const bf16x8*)(X + 14112 + aoff[1] + go);
        bf16x8 M2 = *(const bf16x8*)(X + 14112 + aoff[2] + go);
        bf16x8 L0 = *(const bf16x8*)(X + 28224 + aoff[0] + go);
        bf16x8 L1 = *(const bf16x8*)(X + 28224 + aoff[1] + go);
        bf16x8 L2 = *(const bf16x8*)(X + 28224 + aoff[2] + go);
        bf16x8 Bh = *(const bf16x8*)(W + t*1024 + boff);
        bf16x8 Bm = *(const bf16x8*)(W + 9216 + t*1024 + boff);
        acc0 = MFMA32(M0, Bh, acc0); acc1 = MFMA32(M1, Bh, acc1); acc2 = MFMA32(M2, Bh, acc2);
        acc0 = MFMA32(M0, Bm, acc0); acc1 = MFMA32(M1, Bm, acc1); acc2 = MFMA32(M2, Bm, acc2);
        acc0 = MFMA32(L0, Bh, acc0); acc1 = MFMA32(L1, Bh, acc1); acc2 = MFMA32(L2, Bh, acc2);
      }
    }
    __syncthreads();
  }

  // epilogue: dump partials to LDS, combine G0+G1, bias+leaky+split, store
  float* Lf = (float*)smem;
#define STORE_ACC(A, MT) _Pragma("unroll") \
  for (int r = 0; r < 16; ++r) { \
    int prow = pg*96 + (MT)*32 + 4*kh + (r & 3) + 8*(r >> 2); \
    Lf[(s*384 + prow)*32 + col] = (A)[r]; \
  }
  STORE_ACC(acc0, 0)
  STORE_ACC(acc1, 1)
  STORE_ACC(acc2, 2)
#undef STORE_ACC
  __syncthreads();

  for (int u = tid; u < 5292; u += 512) {
    int pl = u / 1764, rem = u - pl*1764;
    int gq = rem / 441, row = rem - gq*441;
    int y = row/21, xx = row - y*21;
    bf16x8 o = {};
    if (y >= 1 && y <= 19 && xx >= 1 && xx <= 19) {
      int p = (y-1)*19 + xx - 1;
      const float* l0 = Lf + p*32 + gq*8;
      const float* l1 = l0 + 384*32;
      const float* bb = bias + slice*32 + gq*8;
#pragma unroll
      for (int j = 0; j < 8; ++j) {
        float v = l0[j] + l1[j] + bb[j];
        v = v > 0.f ? v : 0.1f*v;
        __bf16 hh = (__bf16)v; float r1 = v - (float)hh;
        __bf16 mm = (__bf16)r1;
        o[j] = pl == 0 ? hh : (pl == 1 ? mm : (__bf16)(r1 - (float)mm));
      }
    }
    *(bf16x8*)(Xd + (((size_t)pl*16 + b)*64 + slice*4 + gq)*GSTR + (size_t)row*8) = o;
  }
}

// ---------------- 1x1 heads on split planes ----------------
__global__ __launch_bounds__(256) void head_rf_k(
    const __bf16* __restrict__ F, const float* __restrict__ wobj,
    const float* __restrict__ bobj, const float* __restrict__ wreg,
    const float* __restrict__ breg, float* __restrict__ obj, float* __restrict__ regp)
{
  int gw = blockIdx.x*4 + (threadIdx.x >> 6);
  if (gw >= NB*NPOS) return;
  int lane = threadIdx.x & 63;
  int b = gw / NPOS, p = gw % NPOS;
  int pp = p + 2*(p/19) + 22;
  const __bf16* base = F + (((size_t)b)*64 + lane)*GSTR + (size_t)pp*8;
  bf16x8 v0 = *(const bf16x8*)base;
  bf16x8 v1 = *(const bf16x8*)(base + PLANE);
  bf16x8 v2 = *(const bf16x8*)(base + 2*PLANE);
  float f[8];
#pragma unroll
  for (int j = 0; j < 8; ++j) f[j] = (float)v0[j] + (float)v1[j] + (float)v2[j];
#pragma unroll
  for (int o = 0; o < 5; ++o) {
    const float* wp = (o == 0) ? wobj : wreg + (o-1)*CCH;
    float4 wa = *(const float4*)(wp + lane*8);
    float4 wb = *(const float4*)(wp + lane*8 + 4);
    float s2 = f[0]*wa.x + f[1]*wa.y + f[2]*wa.z + f[3]*wa.w
             + f[4]*wb.x + f[5]*wb.y + f[6]*wb.z + f[7]*wb.w;
#pragma unroll
    for (int d = 32; d; d >>= 1) s2 += __shfl_xor(s2, d);
    if (lane == 0) {
      if (o == 0) obj[gw] = s2 + bobj[0];
      else regp[(size_t)gw*4 + (o-1)] = s2 + breg[o-1];
    }
  }
}

__global__ __launch_bounds__(256) void head_cls_k(
    const __bf16* __restrict__ F, const float* __restrict__ wcls,
    const float* __restrict__ bcls, float* __restrict__ clsp)
{
  int gw = blockIdx.x*4 + (threadIdx.x >> 6);
  if (gw >= NB*NPOS) return;
  int lane = threadIdx.x & 63;
  int b = gw / NPOS, p = gw % NPOS;
  int pp = p + 2*(p/19) + 22;
  const __bf16* base = F + (((size_t)b)*64 + lane)*GSTR + (size_t)pp*8;
  bf16x8 v0 = *(const bf16x8*)base;
  bf16x8 v1 = *(const bf16x8*)(base + PLANE);
  bf16x8 v2 = *(const bf16x8*)(base + 2*PLANE);
  float f[8];
#pragma unroll
  for (int j = 0; j < 8; ++j) f[j] = (float)v0[j] + (float)v1[j] + (float)v2[j];
#pragma unroll
  for (int o = 0; o < NCLS; ++o) {
    const float* wp = wcls + o*CCH;
    float4 wa = *(const float4*)(wp + lane*8);
    float4 wb = *(const float4*)(wp + lane*8 + 4);
    float s2 = f[0]*wa.x + f[1]*wa.y + f[2]*wa.z + f[3]*wa.w
             + f[4]*wb.x + f[5]*wb.y + f[6]*wb.z + f[7]*wb.w;
#pragma unroll
    for (int d = 32; d; d >>= 1) s2 += __shfl_xor(s2, d);
    if (lane == 0) clsp[(size_t)gw*NCLS + o] = s2 + bcls[o];
  }
}

// ---------------- decode boxes + scores + argmax -------------------------
__global__ void decode_k(const float* __restrict__ obj, const float* __restrict__ clsp,
                         const float* __restrict__ regp, float* __restrict__ outb)
{
  int i = blockIdx.x * 256 + threadIdx.x;
  if (i >= NB * NPOS) return;
  int p = i % NPOS;
  float gx = (float)(p % FMPX), gy = (float)(p / FMPX);
  float4 rg = *(const float4*)&regp[(size_t)i * 4];
  float cx = 1.f / (1.f + expf(-rg.x)) + gx;
  float cy = 1.f / (1.f + expf(-rg.y)) + gy;
  float whw = expf(rg.z), whh = expf(rg.w);
  float x1 = fminf(fmaxf((cx - whw * 0.5f) * BSCALE, 0.f), 1.f);
  float y1 = fminf(fmaxf((cy - whh * 0.5f) * BSCALE, 0.f), 1.f);
  float x2 = fminf(fmaxf((cx + whw * 0.5f) * BSCALE, 0.f), 1.f);
  float y2 = fminf(fmaxf((cy + whh * 0.5f) * BSCALE, 0.f), 1.f);
  outb[(size_t)i * 4 + 0] = x1; outb[(size_t)i * 4 + 1] = y1;
  outb[(size_t)i * 4 + 2] = x2; outb[(size_t)i * 4 + 3] = y2;

  float so = 1.f / (1.f + expf(-obj[i]));
  float cv[20];
  const float4* cp = (const float4*)&clsp[(size_t)i * 20];
#pragma unroll
  for (int q = 0; q < 5; q++) {
    float4 v4 = cp[q];
    cv[q * 4] = v4.x; cv[q * 4 + 1] = v4.y; cv[q * 4 + 2] = v4.z; cv[q * 4 + 3] = v4.w;
  }
  float mx = cv[0];
#pragma unroll
  for (int c = 1; c < 20; c++) mx = fmaxf(mx, cv[c]);
  float sum = 0.f;
#pragma unroll
  for (int c = 0; c < 20; c++) { cv[c] = expf(cv[c] - mx); sum += cv[c]; }
  float inv = so / sum;
  float best = -1.f; int bi = 0;
#pragma unroll
  for (int c = 0; c < 20; c++) { float s = cv[c] * inv; if (s > best) { best = s; bi = c; } }
  outb[SC_OFF + i] = best;
  outb[CLS_OFF + i] = (float)bi;
  outb[KEEP_OFF + i] = 0.f;
}

// ---------------- per (batch,class) greedy NMS ----------------------------
__device__ inline unsigned ordf(float f) {
  unsigned u = __float_as_uint(f);
  return (u & 0x80000000u) ? ~u : (u | 0x80000000u);
}

__global__ __launch_bounds__(64) void nms_k(const float* __restrict__ outb, float* __restrict__ keep_out)
{
  int b = blockIdx.x / NCLS, c = blockIdx.x % NCLS;
  int lane = threadIdx.x;
  __shared__ unsigned long long keys[512];
  __shared__ float bx1[384], by1[384], bx2[384], by2[384], bar[384];
  __shared__ unsigned kp[384];
  __shared__ int sj[384];

  for (int i = lane; i < 512; i += 64) {
    unsigned long long key = 0ULL;
    if (i < NPOS) {
      float sc = outb[SC_OFF + b * NPOS + i];
      int ci = (int)outb[CLS_OFF + b * NPOS + i];
      float s = (ci == c && sc >= CONF_T) ? sc : -1.0f;
      key = ((unsigned long long)ordf(s) << 32) | (unsigned)(~(unsigned)i);
    }
    keys[i] = key;
  }
  __syncthreads();
  for (int kk = 2; kk <= 512; kk <<= 1) {
    for (int jj = kk >> 1; jj > 0; jj >>= 1) {
      for (int i = lane; i < 512; i += 64) {
        int l2 = i ^ jj;
        if (l2 > i) {
          unsigned long long a = keys[i], bb2 = keys[l2];
          bool dir = (i & kk) == 0;
          bool sw = dir ? (a < bb2) : (a > bb2);
          if (sw) { keys[i] = bb2; keys[l2] = a; }
        }
      }
      __syncthreads();
    }
  }
  unsigned ordc = ordf(CONF_T);
  int nvalid = 0;
  for (int i = lane; i < 384; i += 64) {
    unsigned long long key = keys[i];
    unsigned hi = (unsigned)(key >> 32);
    int j = (int)(~(unsigned)key);
    bool valid = (key != 0ULL) && (hi >= ordc);
    kp[i] = valid ? 1u : 0u;
    if (valid) {
      const float* bp = &outb[(size_t)(b * NPOS + j) * 4];
      float x1 = bp[0], y1 = bp[1], x2 = bp[2], y2 = bp[3];
      bx1[i] = x1; by1[i] = y1; bx2[i] = x2; by2[i] = y2;
      bar[i] = (x2 - x1) * (y2 - y1);
      sj[i] = j;
    } else { bx1[i] = 0; by1[i] = 0; bx2[i] = 0; by2[i] = 0; bar[i] = 0; sj[i] = 0; }
    nvalid += __popcll(__ballot(valid));
  }
  __syncthreads();
  for (int i = 0; i < nvalid; ++i) {
    if (kp[i]) {
      float x1i = bx1[i], y1i = by1[i], x2i = bx2[i], y2i = by2[i], ai = bar[i];
      for (int j2 = i + 1 + lane; j2 < nvalid; j2 += 64) {
        if (kp[j2]) {
          float ww = fmaxf(1e-28f, fminf(x2i, bx2[j2]) - fmaxf(x1i, bx1[j2]));
          float hh = fmaxf(1e-28f, fminf(y2i, by2[j2]) - fmaxf(y1i, by1[j2]));
          float inter = ww * hh;
          float iou = inter / (ai + bar[j2] - inter + 1e-14f);
          if (iou > NMS_TH) kp[j2] = 0u;
        }
      }
    }
    __syncthreads();
  }
  for (int i = lane; i < 384; i += 64)
    if (kp[i]) keep_out[b * NPOS + sj[i]] = 1.0f;
}

extern "C" void kernel_launch(void* const* d_in, const int* in_sizes, int n_in,
                              void* d_out, int out_size, void* d_ws, size_t ws_size,
                              hipStream_t stream)
{
  const float* x      = (const float*)d_in[0];
  const float* w_cls1 = (const float*)d_in[1];  const float* b_cls1 = (const float*)d_in[2];
  const float* w_cls2 = (const float*)d_in[3];  const float* b_cls2 = (const float*)d_in[4];
  const float* w_reg1 = (const float*)d_in[5];  const float* b_reg1 = (const float*)d_in[6];
  const float* w_reg2 = (const float*)d_in[7];  const float* b_reg2 = (const float*)d_in[8];
  const float* w_reg3 = (const float*)d_in[9];  const float* b_reg3 = (const float*)d_in[10];
  const float* w_reg4 = (const float*)d_in[11]; const float* b_reg4 = (const float*)d_in[12];
  const float* w_obj  = (const float*)d_in[13]; const float* b_obj  = (const float*)d_in[14];
  const float* w_clsh = (const float*)d_in[15]; const float* b_clsh = (const float*)d_in[16];
  const float* w_regh = (const float*)d_in[17]; const float* b_regh = (const float*)d_in[18];
  float* outb = (float*)d_out;

  __bf16* XsA = (__bf16*)d_ws;
  __bf16* XsB = XsA + 3*PLANE;
  __bf16* Wg  = XsB + 3*PLANE;
  float* obj  = (float*)(Wg + (size_t)7077888);
  float* regp = obj + NB*NPOS;
  float* clsp = regp + (size_t)NB*NPOS*4;

  auto conv = [&](const float* wsrc, const float* bsrc, const __bf16* src, __bf16* dst) {
    repack_k<<<dim3(16, 32), 256, 0, stream>>>(wsrc, Wg);
    conv3x3_mfma<<<256, 512, 0, stream>>>(src, Wg, bsrc, dst);
  };

  split_x_k<<<dim3(64, NB), 256, 0, stream>>>(x, XsA);
  conv(w_reg1, b_reg1, XsA, XsB);
  conv(w_reg2, b_reg2, XsB, XsA);
  conv(w_reg3, b_reg3, XsA, XsB);
  conv(w_reg4, b_reg4, XsB, XsA);                    // rf = XsA
  head_rf_k<<<1444, 256, 0, stream>>>(XsA, w_obj, b_obj, w_regh, b_regh, obj, regp);
  split_x_k<<<dim3(64, NB), 256, 0, stream>>>(x, XsB);
  conv(w_cls1, b_cls1, XsB, XsA);
  conv(w_cls2, b_cls2, XsA, XsB);                    // cf = XsB
  head_cls_k<<<1444, 256, 0, stream>>>(XsB, w_clsh, b_clsh, clsp);
  decode_k<<<(NB * NPOS + 255) / 256, 256, 0, stream>>>(obj, clsp, regp, outb);
  nms_k<<<NB * NCLS, 64, 0, stream>>>(outb, outb + KEEP_OFF);
}

// Round 4
// 1125.315 us; speedup vs baseline: 3.2075x; 1.0678x over previous
//
#include <hip/hip_runtime.h>
#include <hip/hip_bf16.h>
#include <stdint.h>

typedef __bf16 bf16x8 __attribute__((ext_vector_type(8)));
typedef float  f32x16 __attribute__((ext_vector_type(16)));

#define FMPX 19
#define NPOS 361
#define CCH  512
#define NB   16
#define NCLS 20
#define CONF_T 0.001f
#define NMS_TH 0.6f
#define BSCALE (32.0f/608.0f)

#define SC_OFF   (NB*NPOS*4)
#define CLS_OFF  (SC_OFF + NB*NPOS)
#define KEEP_OFF (CLS_OFF + NB*NPOS)

#define GSTR  3528                     // 441 rows * 8 ci elems
#define PLANE ((size_t)3612672)        // 16 b * 64 g * 3528
#define XBUF  42336                    // 3 pl * 2 kh * 441 rows * 16B
#define WBUF  27648                    // 3 pl * 9 tap * 2 kh * 32 co * 16B
#define WOFF  84672                    // 2*XBUF
#define SMEMB 139968                   // 2*XBUF + 2*WBUF

__device__ __forceinline__ void gl_lds16(const void* g, void* l) {
  __builtin_amdgcn_global_load_lds(
      (const __attribute__((address_space(1))) unsigned int*)g,
      (__attribute__((address_space(3))) unsigned int*)l, 16, 0, 0);
}
#define MFMA32(A,B,C) __builtin_amdgcn_mfma_f32_32x32x16_bf16(A,B,C,0,0,0)
#define SBAR() __builtin_amdgcn_sched_barrier(0)

// ---------------- split x: f32 NCHW -> 3 bf16 planes [pl][b][g][row441][8ci]
__global__ void split_x_k(const float* __restrict__ x, __bf16* __restrict__ Xd) {
  __shared__ float sx[8][368];
  int g = blockIdx.x, b = blockIdx.y;
  int tid = threadIdx.x;
  for (int i = tid; i < 8*361; i += 256) {
    int ci = i / 361, p = i - ci*361;
    sx[ci][p] = x[((size_t)b*CCH + g*8 + ci)*NPOS + p];
  }
  __syncthreads();
  for (int row = tid; row < 441; row += 256) {
    int y = row/21, xx = row - y*21;
    bf16x8 oh = {}, om = {}, ol = {};
    if (y >= 1 && y <= 19 && xx >= 1 && xx <= 19) {
      int p = (y-1)*19 + xx - 1;
#pragma unroll
      for (int j = 0; j < 8; ++j) {
        float v = sx[j][p];
        __bf16 hh = (__bf16)v; float r1 = v - (float)hh;
        __bf16 mm = (__bf16)r1;
        oh[j] = hh; om[j] = mm; ol[j] = (__bf16)(r1 - (float)mm);
      }
    }
    size_t o = (((size_t)b)*64 + g)*GSTR + (size_t)row*8;
    *(bf16x8*)(Xd + o)           = oh;
    *(bf16x8*)(Xd + PLANE + o)   = om;
    *(bf16x8*)(Xd + 2*PLANE + o) = ol;
  }
}

// ---------------- weight repack+split: w[co][ci][3][3] f32 ->
//  Wg [slice16][pl3][tap9][chunk32][kh2][co32][8ci] bf16
__global__ void repack_k(const float* __restrict__ w, __bf16* __restrict__ Wg) {
  __shared__ float sw[32][145];
  int slice = blockIdx.x, chunk = blockIdx.y;
  int tid = threadIdx.x;
  for (int i = tid; i < 32*144; i += 256) {
    int cl = i / 144, r = i - cl*144;
    sw[cl][r] = w[((size_t)slice*32 + cl)*4608 + chunk*144 + r];
  }
  __syncthreads();
  for (int u = tid; u < 1728; u += 256) {
    int co = u & 31, kh = (u >> 5) & 1, pt = u >> 6;
    int tap = pt % 9, pl = pt / 9;
    bf16x8 o;
#pragma unroll
    for (int j = 0; j < 8; ++j) {
      float v = sw[co][(kh*8 + j)*9 + tap];
      __bf16 hh = (__bf16)v; float r1 = v - (float)hh;
      __bf16 mm = (__bf16)r1;
      o[j] = pl == 0 ? hh : (pl == 1 ? mm : (__bf16)(r1 - (float)mm));
    }
    *(bf16x8*)(Wg + ((((size_t)slice*3 + pl)*9 + tap)*32 + chunk)*512 + kh*256 + co*8) = o;
  }
}

// ---------------- 3x3 conv via 32x32x16 MFMA, bf16x3 6-product split -------
// grid 256: bid = slice*16 + b ; block 512 (8 waves = 4 pos-groups x 2 psplit)
// inner loop: per-tap register prefetch + sched_barrier fences + setprio MFMA cluster
__global__ __launch_bounds__(512, 2) void conv3x3_mfma(
    const __bf16* __restrict__ Xs, const __bf16* __restrict__ Wg,
    const float* __restrict__ bias, __bf16* __restrict__ Xd)
{
  __shared__ __attribute__((aligned(16))) char smem[SMEMB];
  const int tid = threadIdx.x;
  const int bid = blockIdx.x;
  const int b = bid & 15, slice = bid >> 4;
  const int lane = tid & 63;
  const int wq = __builtin_amdgcn_readfirstlane(tid >> 6);
  const int pg = wq >> 1, s = wq & 1;
  const int col = lane & 31, kh = lane >> 5;
  const int goffs[9] = {-22,-21,-20,-1,0,1,20,21,22};

  // A LDS byte offsets (plane 0, center tap) per m-tile
  int aoff0, aoff1, aoff2;
  {
    int ao[3];
#pragma unroll
    for (int mt = 0; mt < 3; ++mt) {
      int p = pg*96 + mt*32 + col; if (p > 360) p = 360;
      int pp = p + 2*(p/19) + 22;
      ao[mt] = kh*7056 + pp*16;
    }
    aoff0 = ao[0]; aoff1 = ao[1]; aoff2 = ao[2];
  }
  const int boff = kh*512 + col*16;

  // staging source element offsets (chunk 0)
  int xsoff[6];
#pragma unroll
  for (int r = 0; r < 6; ++r) {
    int u = r*512 + tid; if (u > 2645) u = 2645;
    int pl = u / 882, rem = u - pl*882;
    int kh2 = rem / 441, row = rem - kh2*441;
    xsoff[r] = ((pl*16 + b)*64 + kh2)*GSTR + row*8;
  }
  int wsoff[4];
#pragma unroll
  for (int r = 0; r < 4; ++r) {
    int v = r*512 + tid; if (v > 1727) v = 1727;
    int co = v & 31, kh2 = (v >> 5) & 1, pt = v >> 6;
    int tap = pt % 9, pl = pt / 9;
    wsoff[r] = (((slice*3 + pl)*9 + tap)*32)*512 + kh2*256 + co*8;
  }

  auto stage = [&](int c, int buf) {
#pragma unroll
    for (int r = 0; r < 6; ++r)
      if (r*512 + tid < 2646)
        gl_lds16(Xs + xsoff[r] + c*7056, smem + buf*XBUF + (r*512 + wq*64)*16);
#pragma unroll
    for (int r = 0; r < 4; ++r)
      if (r*512 + tid < 1728)
        gl_lds16(Wg + wsoff[r] + c*512, smem + WOFF + buf*WBUF + (r*512 + wq*64)*16);
  };

  f32x16 acc0 = {}, acc1 = {}, acc2 = {};

  stage(0, 0);
  __syncthreads();

  for (int c = 0; c < 32; ++c) {
    const char* X = smem + (c & 1)*XBUF;
    const char* W = smem + WOFF + (c & 1)*WBUF;
    if (c < 31) stage(c + 1, (c + 1) & 1);

    if (s == 0) {
      // products: Ah*Bh, Ah*Bm, Ah*Bl
      bf16x8 A0[2], A1[2], A2[2], B0[2], B1[2], B2[2];
#define LD0(p, t) do { const int _go = goffs[t]*16; \
      A0[p] = *(const bf16x8*)(X + aoff0 + _go); \
      A1[p] = *(const bf16x8*)(X + aoff1 + _go); \
      A2[p] = *(const bf16x8*)(X + aoff2 + _go); \
      B0[p] = *(const bf16x8*)(W + (t)*1024 + boff); \
      B1[p] = *(const bf16x8*)(W + 9216  + (t)*1024 + boff); \
      B2[p] = *(const bf16x8*)(W + 18432 + (t)*1024 + boff); } while (0)
      LD0(0, 0);
#pragma unroll
      for (int t = 0; t < 9; ++t) {
        const int p = t & 1;
        if (t < 8) LD0(p ^ 1, t + 1);
        SBAR();
        __builtin_amdgcn_s_setprio(1);
        acc0 = MFMA32(A0[p], B0[p], acc0);
        acc1 = MFMA32(A1[p], B0[p], acc1);
        acc2 = MFMA32(A2[p], B0[p], acc2);
        acc0 = MFMA32(A0[p], B1[p], acc0);
        acc1 = MFMA32(A1[p], B1[p], acc1);
        acc2 = MFMA32(A2[p], B1[p], acc2);
        acc0 = MFMA32(A0[p], B2[p], acc0);
        acc1 = MFMA32(A1[p], B2[p], acc1);
        acc2 = MFMA32(A2[p], B2[p], acc2);
        __builtin_amdgcn_s_setprio(0);
        SBAR();
      }
#undef LD0
    } else {
      // products: Am*Bh, Am*Bm, Al*Bh
      bf16x8 M0[2], M1[2], M2[2], L0[2], L1[2], L2[2], B0[2], B1[2];
#define LD1(p, t) do { const int _go = goffs[t]*16; \
      M0[p] = *(const bf16x8*)(X + 14112 + aoff0 + _go); \
      M1[p] = *(const bf16x8*)(X + 14112 + aoff1 + _go); \
      M2[p] = *(const bf16x8*)(X + 14112 + aoff2 + _go); \
      L0[p] = *(const bf16x8*)(X + 28224 + aoff0 + _go); \
      L1[p] = *(const bf16x8*)(X + 28224 + aoff1 + _go); \
      L2[p] = *(const bf16x8*)(X + 28224 + aoff2 + _go); \
      B0[p] = *(const bf16x8*)(W + (t)*1024 + boff); \
      B1[p] = *(const bf16x8*)(W + 9216 + (t)*1024 + boff); } while (0)
      LD1(0, 0);
#pragma unroll
      for (int t = 0; t < 9; ++t) {
        const int p = t & 1;
        if (t < 8) LD1(p ^ 1, t + 1);
        SBAR();
        __builtin_amdgcn_s_setprio(1);
        acc0 = MFMA32(M0[p], B0[p], acc0);
        acc1 = MFMA32(M1[p], B0[p], acc1);
        acc2 = MFMA32(M2[p], B0[p], acc2);
        acc0 = MFMA32(M0[p], B1[p], acc0);
        acc1 = MFMA32(M1[p], B1[p], acc1);
        acc2 = MFMA32(M2[p], B1[p], acc2);
        acc0 = MFMA32(L0[p], B0[p], acc0);
        acc1 = MFMA32(L1[p], B0[p], acc1);
        acc2 = MFMA32(L2[p], B0[p], acc2);
        __builtin_amdgcn_s_setprio(0);
        SBAR();
      }
#undef LD1
    }
    __syncthreads();
  }

  // epilogue: dump partials to LDS, combine G0+G1, bias+leaky+split, store
  float* Lf = (float*)smem;
#define STORE_ACC(A, MT) _Pragma("unroll") \
  for (int r = 0; r < 16; ++r) { \
    int prow = pg*96 + (MT)*32 + 4*kh + (r & 3) + 8*(r >> 2); \
    Lf[(s*384 + prow)*32 + col] = (A)[r]; \
  }
  STORE_ACC(acc0, 0)
  STORE_ACC(acc1, 1)
  STORE_ACC(acc2, 2)
#undef STORE_ACC
  __syncthreads();

  for (int u = tid; u < 5292; u += 512) {
    int pl = u / 1764, rem = u - pl*1764;
    int gq = rem / 441, row = rem - gq*441;
    int y = row/21, xx = row - y*21;
    bf16x8 o = {};
    if (y >= 1 && y <= 19 && xx >= 1 && xx <= 19) {
      int p = (y-1)*19 + xx - 1;
      const float* l0 = Lf + p*32 + gq*8;
      const float* l1 = l0 + 384*32;
      const float* bb = bias + slice*32 + gq*8;
#pragma unroll
      for (int j = 0; j < 8; ++j) {
        float v = l0[j] + l1[j] + bb[j];
        v = v > 0.f ? v : 0.1f*v;
        __bf16 hh = (__bf16)v; float r1 = v - (float)hh;
        __bf16 mm = (__bf16)r1;
        o[j] = pl == 0 ? hh : (pl == 1 ? mm : (__bf16)(r1 - (float)mm));
      }
    }
    *(bf16x8*)(Xd + (((size_t)pl*16 + b)*64 + slice*4 + gq)*GSTR + (size_t)row*8) = o;
  }
}

// ---------------- 1x1 heads on split planes ----------------
__global__ __launch_bounds__(256) void head_rf_k(
    const __bf16* __restrict__ F, const float* __restrict__ wobj,
    const float* __restrict__ bobj, const float* __restrict__ wreg,
    const float* __restrict__ breg, float* __restrict__ obj, float* __restrict__ regp)
{
  int gw = blockIdx.x*4 + (threadIdx.x >> 6);
  if (gw >= NB*NPOS) return;
  int lane = threadIdx.x & 63;
  int b = gw / NPOS, p = gw % NPOS;
  int pp = p + 2*(p/19) + 22;
  const __bf16* base = F + (((size_t)b)*64 + lane)*GSTR + (size_t)pp*8;
  bf16x8 v0 = *(const bf16x8*)base;
  bf16x8 v1 = *(const bf16x8*)(base + PLANE);
  bf16x8 v2 = *(const bf16x8*)(base + 2*PLANE);
  float f[8];
#pragma unroll
  for (int j = 0; j < 8; ++j) f[j] = (float)v0[j] + (float)v1[j] + (float)v2[j];
#pragma unroll
  for (int o = 0; o < 5; ++o) {
    const float* wp = (o == 0) ? wobj : wreg + (o-1)*CCH;
    float4 wa = *(const float4*)(wp + lane*8);
    float4 wb = *(const float4*)(wp + lane*8 + 4);
    float s2 = f[0]*wa.x + f[1]*wa.y + f[2]*wa.z + f[3]*wa.w
             + f[4]*wb.x + f[5]*wb.y + f[6]*wb.z + f[7]*wb.w;
#pragma unroll
    for (int d = 32; d; d >>= 1) s2 += __shfl_xor(s2, d);
    if (lane == 0) {
      if (o == 0) obj[gw] = s2 + bobj[0];
      else regp[(size_t)gw*4 + (o-1)] = s2 + breg[o-1];
    }
  }
}

__global__ __launch_bounds__(256) void head_cls_k(
    const __bf16* __restrict__ F, const float* __restrict__ wcls,
    const float* __restrict__ bcls, float* __restrict__ clsp)
{
  int gw = blockIdx.x*4 + (threadIdx.x >> 6);
  if (gw >= NB*NPOS) return;
  int lane = threadIdx.x & 63;
  int b = gw / NPOS, p = gw % NPOS;
  int pp = p + 2*(p/19) + 22;
  const __bf16* base = F + (((size_t)b)*64 + lane)*GSTR + (size_t)pp*8;
  bf16x8 v0 = *(const bf16x8*)base;
  bf16x8 v1 = *(const bf16x8*)(base + PLANE);
  bf16x8 v2 = *(const bf16x8*)(base + 2*PLANE);
  float f[8];
#pragma unroll
  for (int j = 0; j < 8; ++j) f[j] = (float)v0[j] + (float)v1[j] + (float)v2[j];
#pragma unroll
  for (int o = 0; o < NCLS; ++o) {
    const float* wp = wcls + o*CCH;
    float4 wa = *(const float4*)(wp + lane*8);
    float4 wb = *(const float4*)(wp + lane*8 + 4);
    float s2 = f[0]*wa.x + f[1]*wa.y + f[2]*wa.z + f[3]*wa.w
             + f[4]*wb.x + f[5]*wb.y + f[6]*wb.z + f[7]*wb.w;
#pragma unroll
    for (int d = 32; d; d >>= 1) s2 += __shfl_xor(s2, d);
    if (lane == 0) clsp[(size_t)gw*NCLS + o] = s2 + bcls[o];
  }
}

// ---------------- decode boxes + scores + argmax -------------------------
__global__ void decode_k(const float* __restrict__ obj, const float* __restrict__ clsp,
                         const float* __restrict__ regp, float* __restrict__ outb)
{
  int i = blockIdx.x * 256 + threadIdx.x;
  if (i >= NB * NPOS) return;
  int p = i % NPOS;
  float gx = (float)(p % FMPX), gy = (float)(p / FMPX);
  float4 rg = *(const float4*)&regp[(size_t)i * 4];
  float cx = 1.f / (1.f + expf(-rg.x)) + gx;
  float cy = 1.f / (1.f + expf(-rg.y)) + gy;
  float whw = expf(rg.z), whh = expf(rg.w);
  float x1 = fminf(fmaxf((cx - whw * 0.5f) * BSCALE, 0.f), 1.f);
  float y1 = fminf(fmaxf((cy - whh * 0.5f) * BSCALE, 0.f), 1.f);
  float x2 = fminf(fmaxf((cx + whw * 0.5f) * BSCALE, 0.f), 1.f);
  float y2 = fminf(fmaxf((cy + whh * 0.5f) * BSCALE, 0.f), 1.f);
  outb[(size_t)i * 4 + 0] = x1; outb[(size_t)i * 4 + 1] = y1;
  outb[(size_t)i * 4 + 2] = x2; outb[(size_t)i * 4 + 3] = y2;

  float so = 1.f / (1.f + expf(-obj[i]));
  float cv[20];
  const float4* cp = (const float4*)&clsp[(size_t)i * 20];
#pragma unroll
  for (int q = 0; q < 5; q++) {
    float4 v4 = cp[q];
    cv[q * 4] = v4.x; cv[q * 4 + 1] = v4.y; cv[q * 4 + 2] = v4.z; cv[q * 4 + 3] = v4.w;
  }
  float mx = cv[0];
#pragma unroll
  for (int c = 1; c < 20; c++) mx = fmaxf(mx, cv[c]);
  float sum = 0.f;
#pragma unroll
  for (int c = 0; c < 20; c++) { cv[c] = expf(cv[c] - mx); sum += cv[c]; }
  float inv = so / sum;
  float best = -1.f; int bi = 0;
#pragma unroll
  for (int c = 0; c < 20; c++) { float s = cv[c] * inv; if (s > best) { best = s; bi = c; } }
  outb[SC_OFF + i] = best;
  outb[CLS_OFF + i] = (float)bi;
  outb[KEEP_OFF + i] = 0.f;
}

// ---------------- per (batch,class) greedy NMS ----------------------------
__device__ inline unsigned ordf(float f) {
  unsigned u = __float_as_uint(f);
  return (u & 0x80000000u) ? ~u : (u | 0x80000000u);
}

__global__ __launch_bounds__(64) void nms_k(const float* __restrict__ outb, float* __restrict__ keep_out)
{
  int b = blockIdx.x / NCLS, c = blockIdx.x % NCLS;
  int lane = threadIdx.x;
  __shared__ unsigned long long keys[512];
  __shared__ float bx1[384], by1[384], bx2[384], by2[384], bar[384];
  __shared__ unsigned kp[384];
  __shared__ int sj[384];

  for (int i = lane; i < 512; i += 64) {
    unsigned long long key = 0ULL;
    if (i < NPOS) {
      float sc = outb[SC_OFF + b * NPOS + i];
      int ci = (int)outb[CLS_OFF + b * NPOS + i];
      float s = (ci == c && sc >= CONF_T) ? sc : -1.0f;
      key = ((unsigned long long)ordf(s) << 32) | (unsigned)(~(unsigned)i);
    }
    keys[i] = key;
  }
  __syncthreads();
  for (int kk = 2; kk <= 512; kk <<= 1) {
    for (int jj = kk >> 1; jj > 0; jj >>= 1) {
      for (int i = lane; i < 512; i += 64) {
        int l2 = i ^ jj;
        if (l2 > i) {
          unsigned long long a = keys[i], bb2 = keys[l2];
          bool dir = (i & kk) == 0;
          bool sw = dir ? (a < bb2) : (a > bb2);
          if (sw) { keys[i] = bb2; keys[l2] = a; }
        }
      }
      __syncthreads();
    }
  }
  unsigned ordc = ordf(CONF_T);
  int nvalid = 0;
  for (int i = lane; i < 384; i += 64) {
    unsigned long long key = keys[i];
    unsigned hi = (unsigned)(key >> 32);
    int j = (int)(~(unsigned)key);
    bool valid = (key != 0ULL) && (hi >= ordc);
    kp[i] = valid ? 1u : 0u;
    if (valid) {
      const float* bp = &outb[(size_t)(b * NPOS + j) * 4];
      float x1 = bp[0], y1 = bp[1], x2 = bp[2], y2 = bp[3];
      bx1[i] = x1; by1[i] = y1; bx2[i] = x2; by2[i] = y2;
      bar[i] = (x2 - x1) * (y2 - y1);
      sj[i] = j;
    } else { bx1[i] = 0; by1[i] = 0; bx2[i] = 0; by2[i] = 0; bar[i] = 0; sj[i] = 0; }
    nvalid += __popcll(__ballot(valid));
  }
  __syncthreads();
  for (int i = 0; i < nvalid; ++i) {
    if (kp[i]) {
      float x1i = bx1[i], y1i = by1[i], x2i = bx2[i], y2i = by2[i], ai = bar[i];
      for (int j2 = i + 1 + lane; j2 < nvalid; j2 += 64) {
        if (kp[j2]) {
          float ww = fmaxf(1e-28f, fminf(x2i, bx2[j2]) - fmaxf(x1i, bx1[j2]));
          float hh = fmaxf(1e-28f, fminf(y2i, by2[j2]) - fmaxf(y1i, by1[j2]));
          float inter = ww * hh;
          float iou = inter / (ai + bar[j2] - inter + 1e-14f);
          if (iou > NMS_TH) kp[j2] = 0u;
        }
      }
    }
    __syncthreads();
  }
  for (int i = lane; i < 384; i += 64)
    if (kp[i]) keep_out[b * NPOS + sj[i]] = 1.0f;
}

extern "C" void kernel_launch(void* const* d_in, const int* in_sizes, int n_in,
                              void* d_out, int out_size, void* d_ws, size_t ws_size,
                              hipStream_t stream)
{
  const float* x      = (const float*)d_in[0];
  const float* w_cls1 = (const float*)d_in[1];  const float* b_cls1 = (const float*)d_in[2];
  const float* w_cls2 = (const float*)d_in[3];  const float* b_cls2 = (const float*)d_in[4];
  const float* w_reg1 = (const float*)d_in[5];  const float* b_reg1 = (const float*)d_in[6];
  const float* w_reg2 = (const float*)d_in[7];  const float* b_reg2 = (const float*)d_in[8];
  const float* w_reg3 = (const float*)d_in[9];  const float* b_reg3 = (const float*)d_in[10];
  const float* w_reg4 = (const float*)d_in[11]; const float* b_reg4 = (const float*)d_in[12];
  const float* w_obj  = (const float*)d_in[13]; const float* b_obj  = (const float*)d_in[14];
  const float* w_clsh = (const float*)d_in[15]; const float* b_clsh = (const float*)d_in[16];
  const float* w_regh = (const float*)d_in[17]; const float* b_regh = (const float*)d_in[18];
  float* outb = (float*)d_out;

  __bf16* XsA = (__bf16*)d_ws;
  __bf16* XsB = XsA + 3*PLANE;
  __bf16* Wg  = XsB + 3*PLANE;
  float* obj  = (float*)(Wg + (size_t)7077888);
  float* regp = obj + NB*NPOS;
  float* clsp = regp + (size_t)NB*NPOS*4;

  auto conv = [&](const float* wsrc, const float* bsrc, const __bf16* src, __bf16* dst) {
    repack_k<<<dim3(16, 32), 256, 0, stream>>>(wsrc, Wg);
    conv3x3_mfma<<<256, 512, 0, stream>>>(src, Wg, bsrc, dst);
  };

  split_x_k<<<dim3(64, NB), 256, 0, stream>>>(x, XsA);
  conv(w_reg1, b_reg1, XsA, XsB);
  conv(w_reg2, b_reg2, XsB, XsA);
  conv(w_reg3, b_reg3, XsA, XsB);
  conv(w_reg4, b_reg4, XsB, XsA);                    // rf = XsA
  head_rf_k<<<1444, 256, 0, stream>>>(XsA, w_obj, b_obj, w_regh, b_regh, obj, regp);
  split_x_k<<<dim3(64, NB), 256, 0, stream>>>(x, XsB);
  conv(w_cls1, b_cls1, XsB, XsA);
  conv(w_cls2, b_cls2, XsA, XsB);                    // cf = XsB
  head_cls_k<<<1444, 256, 0, stream>>>(XsB, w_clsh, b_clsh, clsp);
  decode_k<<<(NB * NPOS + 255) / 256, 256, 0, stream>>>(obj, clsp, regp, outb);
  nms_k<<<NB * NCLS, 64, 0, stream>>>(outb, outb + KEEP_OFF);
}